// Round 9
// baseline (75.985 us; speedup 1.0000x reference)
//
#include <hip/hip_runtime.h>

#define LOG2E 1.4426950408889634f
#define SCALE (2.0f * LOG2E)

__device__ __forceinline__ float fast_exp2(float x) { return __builtin_amdgcn_exp2f(x); }
__device__ __forceinline__ float fast_rcp(float x)  { return __builtin_amdgcn_rcpf(x); }

typedef __attribute__((ext_vector_type(8))) short bf16x8;
typedef __attribute__((ext_vector_type(4))) float f32x4;

// ---------------- stage 0: pack A/B into bf16 hi/lo MFMA fragment panels ----------------
// Logical GEMM: C[m,n] = sum_{kp=0}^{1535} A[m,kp]*B[n,kp]
//   kp segment 0: x_hi*w_hi ; 1: x_lo*w_hi ; 2: x_hi*w_lo   (lo*lo dropped, ~1e-5 rel)
// Panel layout (ushort): [tb][kt(24)][ks(2)][frag(4)][lane(64)][j(8)]
__global__ __launch_bounds__(256) void pack_kernel(const float* __restrict__ inputs,
                                                   const float* __restrict__ attn_W,
                                                   ushort* __restrict__ Ap,
                                                   ushort* __restrict__ Bp) {
    int tid = blockIdx.x * 256 + threadIdx.x;
    const bool isA = tid < 393216;
    int f = isA ? tid : tid - 393216;
    int l  = f & 63;
    int fr = (f >> 6) & 3;
    int ks = (f >> 8) & 1;
    int rem = f >> 9;
    int kt = rem % 24, tb = rem / 24;
    int kp = kt * 64 + ks * 32 + (l >> 4) * 8;
    int seg = kp >> 9, k = kp & 511;
    const float* src;
    bool useLo;
    if (isA) {
        int m = tb * 64 + fr * 16 + (l & 15);
        src = inputs + ((m & 255) * 8 + (m >> 8)) * 512 + k;
        useLo = (seg == 1);
    } else {
        int n = tb * 64 + fr * 16 + (l & 15);
        src = attn_W + (n & 511) * 1024 + (n >> 9) * 512 + k;
        useLo = (seg == 2);
    }
    float4 v0 = *(const float4*)src;
    float4 v1 = *(const float4*)(src + 4);
    float vv[8] = {v0.x, v0.y, v0.z, v0.w, v1.x, v1.y, v1.z, v1.w};
    ushort o[8];
#pragma unroll
    for (int j = 0; j < 8; ++j) {
        unsigned u = __float_as_uint(vv[j]);
        unsigned hi = (u + 0x7FFF + ((u >> 16) & 1)) >> 16;   // RN bf16
        if (useLo) {
            float lo = vv[j] - __uint_as_float(hi << 16);
            unsigned ul = __float_as_uint(lo);
            o[j] = (ushort)((ul + 0x7FFF + ((ul >> 16) & 1)) >> 16);
        } else {
            o[j] = (ushort)hi;
        }
    }
    ushort* dst = (isA ? Ap : Bp) + (long)f * 8;
    *(uint4*)dst = *(const uint4*)o;
}

// ---------------- stage 1: MFMA GEMM, 256x128 tile, 8 waves (4x2), BK=64 dbuf ----------------
// 64 blocks; mt = bid&7 so the 8 blocks sharing an A-tile land on one XCD (L2 reuse).
// Panels chunked [tb][kt][4096 ushort] -> staging is 6 linear 8KB copies per kt.
__global__ __launch_bounds__(512) void mfma_gemm(const ushort* __restrict__ Ap,
                                                 const ushort* __restrict__ Bp,
                                                 const float* __restrict__ attn_b,
                                                 float* __restrict__ E1,
                                                 float* __restrict__ E2) {
    const int mt = blockIdx.x & 7;    // 8 m-tiles of 256 rows
    const int nb = blockIdx.x >> 3;   // 8 n-tiles of 128 cols
    __shared__ ushort lds[2][24576];  // per buf: A tb0..3 (4x4096) | B tb0..1 (2x4096)

    const int t = threadIdx.x;
    const int lane = t & 63, w = t >> 6;
    const int wrm = w >> 1, wcn = w & 1;   // wave tile 64(m) x 64(n)

    const ushort* aBase = Ap + (long)(mt * 4) * 98304;
    const ushort* bBase = Bp + (long)(nb * 2) * 98304;

    f32x4 acc[4][4];
#pragma unroll
    for (int i = 0; i < 4; ++i)
#pragma unroll
        for (int j = 0; j < 4; ++j)
            acc[i][j] = (f32x4){0.f, 0.f, 0.f, 0.f};

    uint4 st[6];
#define LOADK(kt)                                                              \
    {                                                                          \
        st[0] = *(const uint4*)(aBase + 0 * 98304 + (kt) * 4096 + t * 8);      \
        st[1] = *(const uint4*)(aBase + 1 * 98304 + (kt) * 4096 + t * 8);      \
        st[2] = *(const uint4*)(aBase + 2 * 98304 + (kt) * 4096 + t * 8);      \
        st[3] = *(const uint4*)(aBase + 3 * 98304 + (kt) * 4096 + t * 8);      \
        st[4] = *(const uint4*)(bBase + 0 * 98304 + (kt) * 4096 + t * 8);      \
        st[5] = *(const uint4*)(bBase + 1 * 98304 + (kt) * 4096 + t * 8);      \
    }
#define STOREK(buf)                                                            \
    {                                                                          \
        ushort* d = lds[buf];                                                  \
        *(uint4*)(d + 0 * 4096 + t * 8) = st[0];                               \
        *(uint4*)(d + 1 * 4096 + t * 8) = st[1];                               \
        *(uint4*)(d + 2 * 4096 + t * 8) = st[2];                               \
        *(uint4*)(d + 3 * 4096 + t * 8) = st[3];                               \
        *(uint4*)(d + 4 * 4096 + t * 8) = st[4];                               \
        *(uint4*)(d + 5 * 4096 + t * 8) = st[5];                               \
    }

    LOADK(0);
    STOREK(0);
    __syncthreads();

    for (int kt = 0; kt < 24; ++kt) {
        const int cur = kt & 1;
        if (kt < 23) LOADK(kt + 1);
        const ushort* buf = lds[cur];
#pragma unroll
        for (int ks = 0; ks < 2; ++ks) {
            bf16x8 a[4], b[4];
#pragma unroll
            for (int mf = 0; mf < 4; ++mf)
                a[mf] = *(const bf16x8*)&buf[wrm * 4096 + ks * 2048 + mf * 512 + lane * 8];
#pragma unroll
            for (int nf = 0; nf < 4; ++nf)
                b[nf] = *(const bf16x8*)&buf[(4 + wcn) * 4096 + ks * 2048 + nf * 512 + lane * 8];
#pragma unroll
            for (int mf = 0; mf < 4; ++mf)
#pragma unroll
                for (int nf = 0; nf < 4; ++nf)
                    acc[mf][nf] = __builtin_amdgcn_mfma_f32_16x16x32_bf16(
                        a[mf], b[nf], acc[mf][nf], 0, 0, 0);
        }
        if (kt < 23) {
            STOREK(cur ^ 1);
        }
        __syncthreads();
    }
#undef LOADK
#undef STOREK

    // epilogue: D col = lane&15, row = (lane>>4)*4 + r  (m89-verified layout)
#pragma unroll
    for (int nf = 0; nf < 4; ++nf) {
        int n = nb * 128 + wcn * 64 + nf * 16 + (lane & 15);
        const bool isE1 = (n < 512);
        float* dst = isE1 ? E1 : E2;
        int o = n & 511;
        float bias = isE1 ? attn_b[o] : 0.0f;
#pragma unroll
        for (int mf = 0; mf < 4; ++mf) {
            int ml = mt * 256 + wrm * 64 + mf * 16 + ((lane >> 4) << 2);
            int bb = ml >> 8, l = ml & 255;
            long rowoff = ((long)(bb * 8 + (l >> 5)) * 512 + o) * 32 + (l & 31);
#pragma unroll
            for (int r = 0; r < 4; ++r)
                dst[rowoff + r] = fast_exp2(SCALE * (acc[mf][nf][r] + bias));
        }
    }
}

// ---------------- stage 2: partial energies (R4-exact) ----------------
// EP[s][b][i][j] = sum_{o in chunk s (128)} c_o * rcp(1 + E1[b,i,o]*E2[b,j,o])
__global__ __launch_bounds__(256) void energy_kernel(const float* __restrict__ E1,
                                                     const float* __restrict__ E2,
                                                     const float* __restrict__ sW,
                                                     float* __restrict__ EP) {
    const int bid = blockIdx.x;       // 2048 = 8 b * 8 ti * 8 tj * 4 s
    const int s  = bid & 3;
    const int tj = (bid >> 2) & 7;
    const int ti = (bid >> 5) & 7;
    const int b  = bid >> 8;
    __shared__ float p1s[64 * 32];
    __shared__ float p2s[64 * 32];
    __shared__ float csh[128];

    const int t = threadIdx.x;
    const int tx = t & 15, ty = t >> 4;

    if (t < 128) csh[t] = 2.0f * sW[s * 128 + t];

    const float* p1base = E1 + ((long)(b * 8 + ti) * 512 + s * 128) * 32;
    const float* p2base = E2 + ((long)(b * 8 + tj) * 512 + s * 128) * 32;

    float acc00 = 0.f, acc01 = 0.f, acc10 = 0.f, acc11 = 0.f;

    for (int c0 = 0; c0 < 128; c0 += 64) {
        __syncthreads();
        const float4* s1 = (const float4*)(p1base + c0 * 32);
        const float4* s2 = (const float4*)(p2base + c0 * 32);
        float4* d1 = (float4*)p1s;
        float4* d2 = (float4*)p2s;
        d1[t] = s1[t];  d1[256 + t] = s1[256 + t];
        d2[t] = s2[t];  d2[256 + t] = s2[256 + t];
        __syncthreads();
#pragma unroll 8
        for (int hh = 0; hh < 64; ++hh) {
            float c = csh[c0 + hh];
            float2 a  = *(const float2*)&p1s[hh * 32 + ty * 2];
            float2 bj = *(const float2*)&p2s[hh * 32 + tx * 2];
            acc00 = fmaf(c, fast_rcp(fmaf(a.x, bj.x, 1.0f)), acc00);
            acc01 = fmaf(c, fast_rcp(fmaf(a.x, bj.y, 1.0f)), acc01);
            acc10 = fmaf(c, fast_rcp(fmaf(a.y, bj.x, 1.0f)), acc10);
            acc11 = fmaf(c, fast_rcp(fmaf(a.y, bj.y, 1.0f)), acc11);
        }
    }

    float* Eb = EP + (long)s * 524288 + (long)b * 65536 + (ti * 32) * 256 + tj * 32;
    *(float2*)&Eb[(ty * 2 + 0) * 256 + tx * 2] = make_float2(acc00, acc01);
    *(float2*)&Eb[(ty * 2 + 1) * 256 + tx * 2] = make_float2(acc10, acc11);
}

// ---------------- stage 3: combine partials + softmax over i (axis=1) ----------------
__global__ __launch_bounds__(256) void softmax_kernel(const float* __restrict__ P0,
                                                      const float* __restrict__ P1,
                                                      const float* __restrict__ P2,
                                                      const float* __restrict__ P3,
                                                      float* __restrict__ out) {
    const int b  = blockIdx.x >> 4;
    const int jt = blockIdx.x & 15;
    const int t  = threadIdx.x;
    const int jx = t & 15;
    const int iy = t >> 4;
    const long base = (long)b * 65536 + jt * 16 + jx;

    float v[16];
#pragma unroll
    for (int k = 0; k < 16; ++k) {
        long idx = base + (long)(iy + k * 16) * 256;
        v[k] = -(P0[idx] + P1[idx] + P2[idx] + P3[idx]);
    }

    float m = v[0];
#pragma unroll
    for (int k = 1; k < 16; ++k) m = fmaxf(m, v[k]);

    __shared__ float red[256];
    red[t] = m;
    __syncthreads();
    if (t < 128) red[t] = fmaxf(red[t], red[t + 128]);
    __syncthreads();
    if (t < 64) red[t] = fmaxf(red[t], red[t + 64]);
    __syncthreads();
    if (t < 32) red[t] = fmaxf(red[t], red[t + 32]);
    __syncthreads();
    if (t < 16) red[t] = fmaxf(red[t], red[t + 16]);
    __syncthreads();
    m = red[jx];
    __syncthreads();

    float ssum = 0.f;
#pragma unroll
    for (int k = 0; k < 16; ++k) {
        v[k] = fast_exp2((v[k] - m) * LOG2E);
        ssum += v[k];
    }
    red[t] = ssum;
    __syncthreads();
    if (t < 128) red[t] += red[t + 128];
    __syncthreads();
    if (t < 64) red[t] += red[t + 64];
    __syncthreads();
    if (t < 32) red[t] += red[t + 32];
    __syncthreads();
    if (t < 16) red[t] += red[t + 16];
    __syncthreads();
    float inv = fast_rcp(red[jx]);

#pragma unroll
    for (int k = 0; k < 16; ++k) {
        long idx = base + (long)(iy + k * 16) * 256;
        out[idx] = v[k] * inv;
    }
}

extern "C" void kernel_launch(void* const* d_in, const int* in_sizes, int n_in,
                              void* d_out, int out_size, void* d_ws, size_t ws_size,
                              hipStream_t stream) {
    const float* inputs  = (const float*)d_in[0];  // (256, 8, 512)
    const float* attn_W  = (const float*)d_in[1];  // (512, 1024)
    const float* attn_b  = (const float*)d_in[2];  // (512,)
    const float* score_W = (const float*)d_in[3];  // (1, 512)
    float* out = (float*)d_out;                    // (8, 256, 256)

    float* ws = (float*)d_ws;
    float* E1 = ws;                                // 1M f32 exp panel
    float* E2 = ws + (1 << 20);                    // 1M f32
    float* EP = ws + (2 << 20);                    // 4 * 512K f32 partials (8 MB)
    ushort* Ap = (ushort*)(ws + (4 << 20));        // 3.146M bf16
    ushort* Bp = Ap + 3145728;                     // 1.573M bf16

    pack_kernel<<<2304, 256, 0, stream>>>(inputs, attn_W, Ap, Bp);
    mfma_gemm<<<64, 512, 0, stream>>>(Ap, Bp, attn_b, E1, E2);
    energy_kernel<<<2048, 256, 0, stream>>>(E1, E2, score_W, EP);
    softmax_kernel<<<128, 256, 0, stream>>>(EP, EP + 524288, EP + 2 * 524288,
                                            EP + 3 * 524288, out);
}

// Round 10
// 67.827 us; speedup vs baseline: 1.1203x; 1.1203x over previous
//
#include <hip/hip_runtime.h>

#define LOG2E 1.4426950408889634f
#define SCALE (2.0f * LOG2E)

__device__ __forceinline__ float fast_exp2(float x) { return __builtin_amdgcn_exp2f(x); }
__device__ __forceinline__ float fast_rcp(float x)  { return __builtin_amdgcn_rcpf(x); }

typedef __attribute__((ext_vector_type(8))) short bf16x8;
typedef __attribute__((ext_vector_type(4))) float f32x4;

// ---------------- stage 0: pack A/B into bf16 hi/lo MFMA fragment panels ----------------
// Logical GEMM: C[m,n] = sum_{kp=0}^{1535} A[m,kp]*B[n,kp]
//   A segs: 0:x_hi 1:x_lo 2:x_hi ; B segs: 0:w_hi 1:w_hi 2:w_lo  (lo*lo dropped, ~1e-5 rel)
// Panel layout (ushort): [tb][kt(24)][ks(2)][frag(4)][lane(64)][j(8)], 98304/tb.
// v2: tid iterates SOURCE memory order (wave reads 2KB contiguous), scatters 3x16B writes.
__global__ __launch_bounds__(256) void pack_kernel(const float* __restrict__ inputs,
                                                   const float* __restrict__ attn_W,
                                                   ushort* __restrict__ Ap,
                                                   ushort* __restrict__ Bp) {
    const int tid = blockIdx.x * 256 + threadIdx.x;
    const bool isA = tid < 131072;
    const float* src;
    int rowmn, k8;
    if (isA) {
        k8 = tid & 63;                       // 8-float chunk within k-row
        int row = tid >> 6;                  // = l*8 + b (source row order)
        src = inputs + (long)row * 512 + k8 * 8;
        rowmn = (row & 7) * 256 + (row >> 3);   // m = b*256 + l
    } else {
        int f = tid - 131072;
        int c8 = f & 127;                    // chunk within the 1024-wide W row
        int r  = f >> 7;
        src = attn_W + (long)r * 1024 + c8 * 8;
        k8 = c8 & 63;
        rowmn = (c8 < 64) ? r : r + 512;     // n (W1 cols | W2 cols)
    }

    float4 v0 = *(const float4*)src;
    float4 v1 = *(const float4*)(src + 4);
    float vv[8] = {v0.x, v0.y, v0.z, v0.w, v1.x, v1.y, v1.z, v1.w};
    ushort hi8[8], lo8[8];
#pragma unroll
    for (int j = 0; j < 8; ++j) {
        unsigned u = __float_as_uint(vv[j]);
        unsigned h = (u + 0x7FFF + ((u >> 16) & 1)) >> 16;   // RN bf16
        hi8[j] = (ushort)h;
        float lo = vv[j] - __uint_as_float(h << 16);
        unsigned ul = __float_as_uint(lo);
        lo8[j] = (ushort)((ul + 0x7FFF + ((ul >> 16) & 1)) >> 16);
    }

    const int tb = rowmn >> 6, fr = (rowmn >> 4) & 3, ml = rowmn & 15;
    ushort* P = isA ? Ap : Bp;
    const long base = (long)tb * 98304 + fr * 512 + ml * 8;
#pragma unroll
    for (int s = 0; s < 3; ++s) {
        int kp8 = s * 64 + k8;
        int kt = kp8 >> 3, r8 = kp8 & 7;
        long off = base + (long)kt * 4096 + (r8 >> 2) * 2048 + (r8 & 3) * 128;
        const ushort* sel = isA ? (s == 1 ? lo8 : hi8) : (s == 2 ? lo8 : hi8);
        *(uint4*)(P + off) = *(const uint4*)sel;
    }
}

// ---------------- stage 1: MFMA GEMM, tile 128x64, 4 waves 2x2, BK=64 dbuf (R4 best) ----
__global__ __launch_bounds__(256) void mfma_gemm(const ushort* __restrict__ Ap,
                                                 const ushort* __restrict__ Bp,
                                                 const float* __restrict__ attn_b,
                                                 float* __restrict__ E1,
                                                 float* __restrict__ E2) {
    const int mb = blockIdx.x & 15;
    const int nb = blockIdx.x >> 4;
    __shared__ ushort lds[2][12288];

    const int t = threadIdx.x;
    const int lane = t & 63, w = t >> 6;
    const int wr = w >> 1, wc = w & 1;

    const ushort* A0 = Ap + (long)(mb * 2 + 0) * 98304;
    const ushort* A1 = Ap + (long)(mb * 2 + 1) * 98304;
    const ushort* B0 = Bp + (long)nb * 98304;

    f32x4 acc[4][2];
#pragma unroll
    for (int i = 0; i < 4; ++i)
#pragma unroll
        for (int j = 0; j < 2; ++j)
            acc[i][j] = (f32x4){0.f, 0.f, 0.f, 0.f};

    uint4 st[6];
    st[0] = ((const uint4*)A0)[t];       st[1] = ((const uint4*)A0)[t + 256];
    st[2] = ((const uint4*)A1)[t];       st[3] = ((const uint4*)A1)[t + 256];
    st[4] = ((const uint4*)B0)[t];       st[5] = ((const uint4*)B0)[t + 256];
#pragma unroll
    for (int r = 0; r < 6; ++r) ((uint4*)lds[0])[t + r * 256] = st[r];
    __syncthreads();

    for (int kt = 0; kt < 24; ++kt) {
        if (kt < 23) {
            const uint4* a0 = (const uint4*)(A0 + (kt + 1) * 4096);
            const uint4* a1 = (const uint4*)(A1 + (kt + 1) * 4096);
            const uint4* b0 = (const uint4*)(B0 + (kt + 1) * 4096);
            st[0] = a0[t]; st[1] = a0[t + 256];
            st[2] = a1[t]; st[3] = a1[t + 256];
            st[4] = b0[t]; st[5] = b0[t + 256];
        }
        const ushort* buf = lds[kt & 1];
#pragma unroll
        for (int ks = 0; ks < 2; ++ks) {
            bf16x8 a[4], b[2];
#pragma unroll
            for (int mf = 0; mf < 4; ++mf)
                a[mf] = *(const bf16x8*)&buf[wr * 4096 + ks * 2048 + mf * 512 + lane * 8];
#pragma unroll
            for (int nn = 0; nn < 2; ++nn)
                b[nn] = *(const bf16x8*)&buf[8192 + ks * 2048 + (wc * 2 + nn) * 512 + lane * 8];
#pragma unroll
            for (int mf = 0; mf < 4; ++mf)
#pragma unroll
                for (int nn = 0; nn < 2; ++nn)
                    acc[mf][nn] = __builtin_amdgcn_mfma_f32_16x16x32_bf16(
                        a[mf], b[nn], acc[mf][nn], 0, 0, 0);
        }
        if (kt < 23) {
            ushort* nbuf = lds[(kt + 1) & 1];
#pragma unroll
            for (int r = 0; r < 6; ++r) ((uint4*)nbuf)[t + r * 256] = st[r];
            __syncthreads();
        }
    }

    const bool isE1 = (nb < 8);
    float* dst = isE1 ? E1 : E2;
    const int b = mb >> 1;
#pragma unroll
    for (int nn = 0; nn < 2; ++nn) {
        int n = nb * 64 + wc * 32 + nn * 16 + (lane & 15);
        int o = n & 511;
        float bias = isE1 ? attn_b[o] : 0.0f;
#pragma unroll
        for (int mf = 0; mf < 4; ++mf) {
            int ti = (mb & 1) * 4 + wr * 2 + (mf >> 1);
            int iibase = (mf & 1) * 16 + (lane >> 4) * 4;
            long rowoff = ((long)(b * 8 + ti) * 512 + o) * 32 + iibase;
#pragma unroll
            for (int r = 0; r < 4; ++r)
                dst[rowoff + r] = fast_exp2(SCALE * (acc[mf][nn][r] + bias));
        }
    }
}

// ---------------- stage 2: partial energies (R4-exact) ----------------
// EP[s][b][i][j] = sum_{o in chunk s (128)} c_o * rcp(1 + E1[b,i,o]*E2[b,j,o])
__global__ __launch_bounds__(256) void energy_kernel(const float* __restrict__ E1,
                                                     const float* __restrict__ E2,
                                                     const float* __restrict__ sW,
                                                     float* __restrict__ EP) {
    const int bid = blockIdx.x;       // 2048 = 8 b * 8 ti * 8 tj * 4 s
    const int s  = bid & 3;
    const int tj = (bid >> 2) & 7;
    const int ti = (bid >> 5) & 7;
    const int b  = bid >> 8;
    __shared__ float p1s[64 * 32];
    __shared__ float p2s[64 * 32];
    __shared__ float csh[128];

    const int t = threadIdx.x;
    const int tx = t & 15, ty = t >> 4;

    if (t < 128) csh[t] = 2.0f * sW[s * 128 + t];

    const float* p1base = E1 + ((long)(b * 8 + ti) * 512 + s * 128) * 32;
    const float* p2base = E2 + ((long)(b * 8 + tj) * 512 + s * 128) * 32;

    float acc00 = 0.f, acc01 = 0.f, acc10 = 0.f, acc11 = 0.f;

    for (int c0 = 0; c0 < 128; c0 += 64) {
        __syncthreads();
        const float4* s1 = (const float4*)(p1base + c0 * 32);
        const float4* s2 = (const float4*)(p2base + c0 * 32);
        float4* d1 = (float4*)p1s;
        float4* d2 = (float4*)p2s;
        d1[t] = s1[t];  d1[256 + t] = s1[256 + t];
        d2[t] = s2[t];  d2[256 + t] = s2[256 + t];
        __syncthreads();
#pragma unroll 8
        for (int hh = 0; hh < 64; ++hh) {
            float c = csh[c0 + hh];
            float2 a  = *(const float2*)&p1s[hh * 32 + ty * 2];
            float2 bj = *(const float2*)&p2s[hh * 32 + tx * 2];
            acc00 = fmaf(c, fast_rcp(fmaf(a.x, bj.x, 1.0f)), acc00);
            acc01 = fmaf(c, fast_rcp(fmaf(a.x, bj.y, 1.0f)), acc01);
            acc10 = fmaf(c, fast_rcp(fmaf(a.y, bj.x, 1.0f)), acc10);
            acc11 = fmaf(c, fast_rcp(fmaf(a.y, bj.y, 1.0f)), acc11);
        }
    }

    float* Eb = EP + (long)s * 524288 + (long)b * 65536 + (ti * 32) * 256 + tj * 32;
    *(float2*)&Eb[(ty * 2 + 0) * 256 + tx * 2] = make_float2(acc00, acc01);
    *(float2*)&Eb[(ty * 2 + 1) * 256 + tx * 2] = make_float2(acc10, acc11);
}

// ---------------- stage 3: combine partials + softmax over i (axis=1) ----------------
__global__ __launch_bounds__(256) void softmax_kernel(const float* __restrict__ P0,
                                                      const float* __restrict__ P1,
                                                      const float* __restrict__ P2,
                                                      const float* __restrict__ P3,
                                                      float* __restrict__ out) {
    const int b  = blockIdx.x >> 4;
    const int jt = blockIdx.x & 15;
    const int t  = threadIdx.x;
    const int jx = t & 15;
    const int iy = t >> 4;
    const long base = (long)b * 65536 + jt * 16 + jx;

    float v[16];
#pragma unroll
    for (int k = 0; k < 16; ++k) {
        long idx = base + (long)(iy + k * 16) * 256;
        v[k] = -(P0[idx] + P1[idx] + P2[idx] + P3[idx]);
    }

    float m = v[0];
#pragma unroll
    for (int k = 1; k < 16; ++k) m = fmaxf(m, v[k]);

    __shared__ float red[256];
    red[t] = m;
    __syncthreads();
    if (t < 128) red[t] = fmaxf(red[t], red[t + 128]);
    __syncthreads();
    if (t < 64) red[t] = fmaxf(red[t], red[t + 64]);
    __syncthreads();
    if (t < 32) red[t] = fmaxf(red[t], red[t + 32]);
    __syncthreads();
    if (t < 16) red[t] = fmaxf(red[t], red[t + 16]);
    __syncthreads();
    m = red[jx];
    __syncthreads();

    float ssum = 0.f;
#pragma unroll
    for (int k = 0; k < 16; ++k) {
        v[k] = fast_exp2((v[k] - m) * LOG2E);
        ssum += v[k];
    }
    red[t] = ssum;
    __syncthreads();
    if (t < 128) red[t] += red[t + 128];
    __syncthreads();
    if (t < 64) red[t] += red[t + 64];
    __syncthreads();
    if (t < 32) red[t] += red[t + 32];
    __syncthreads();
    if (t < 16) red[t] += red[t + 16];
    __syncthreads();
    float inv = fast_rcp(red[jx]);

#pragma unroll
    for (int k = 0; k < 16; ++k) {
        long idx = base + (long)(iy + k * 16) * 256;
        out[idx] = v[k] * inv;
    }
}

extern "C" void kernel_launch(void* const* d_in, const int* in_sizes, int n_in,
                              void* d_out, int out_size, void* d_ws, size_t ws_size,
                              hipStream_t stream) {
    const float* inputs  = (const float*)d_in[0];  // (256, 8, 512)
    const float* attn_W  = (const float*)d_in[1];  // (512, 1024)
    const float* attn_b  = (const float*)d_in[2];  // (512,)
    const float* score_W = (const float*)d_in[3];  // (1, 512)
    float* out = (float*)d_out;                    // (8, 256, 256)

    float* ws = (float*)d_ws;
    float* E1 = ws;                                // 1M f32 exp panel
    float* E2 = ws + (1 << 20);                    // 1M f32
    float* EP = ws + (2 << 20);                    // 4 * 512K f32 partials (8 MB)
    ushort* Ap = (ushort*)(ws + (4 << 20));        // 3.146M bf16
    ushort* Bp = Ap + 3145728;                     // 1.573M bf16

    pack_kernel<<<768, 256, 0, stream>>>(inputs, attn_W, Ap, Bp);
    mfma_gemm<<<256, 256, 0, stream>>>(Ap, Bp, attn_b, E1, E2);
    energy_kernel<<<2048, 256, 0, stream>>>(E1, E2, score_W, EP);
    softmax_kernel<<<128, 256, 0, stream>>>(EP, EP + 524288, EP + 2 * 524288,
                                            EP + 3 * 524288, out);
}

// Round 11
// 66.183 us; speedup vs baseline: 1.1481x; 1.0248x over previous
//
#include <hip/hip_runtime.h>

#define LOG2E 1.4426950408889634f
#define SCALE (2.0f * LOG2E)

__device__ __forceinline__ float fast_exp2(float x) { return __builtin_amdgcn_exp2f(x); }
__device__ __forceinline__ float fast_rcp(float x)  { return __builtin_amdgcn_rcpf(x); }

typedef __attribute__((ext_vector_type(8))) short bf16x8;
typedef __attribute__((ext_vector_type(4))) float f32x4;

// ---------------- stage 0: pack A/B into bf16 hi/lo MFMA fragment panels ----------------
// Logical GEMM: C[m,n] = sum_{kp=0}^{1535} A[m,kp]*B[n,kp]
//   A segs: 0:x_hi 1:x_lo 2:x_hi ; B segs: 0:w_hi 1:w_hi 2:w_lo  (lo*lo dropped, ~1e-5 rel)
// Panel layout (ushort): [tb][kt(24)][ks(2)][frag(4)][lane(64)][j(8)], 98304/tb.
// tid iterates SOURCE memory order (wave reads 2KB contiguous), scatters 3x16B writes.
__global__ __launch_bounds__(256) void pack_kernel(const float* __restrict__ inputs,
                                                   const float* __restrict__ attn_W,
                                                   ushort* __restrict__ Ap,
                                                   ushort* __restrict__ Bp) {
    const int tid = blockIdx.x * 256 + threadIdx.x;
    const bool isA = tid < 131072;
    const float* src;
    int rowmn, k8;
    if (isA) {
        k8 = tid & 63;                       // 8-float chunk within k-row
        int row = tid >> 6;                  // = l*8 + b (source row order)
        src = inputs + (long)row * 512 + k8 * 8;
        rowmn = (row & 7) * 256 + (row >> 3);   // m = b*256 + l
    } else {
        int f = tid - 131072;
        int c8 = f & 127;                    // chunk within the 1024-wide W row
        int r  = f >> 7;
        src = attn_W + (long)r * 1024 + c8 * 8;
        k8 = c8 & 63;
        rowmn = (c8 < 64) ? r : r + 512;     // n (W1 cols | W2 cols)
    }

    float4 v0 = *(const float4*)src;
    float4 v1 = *(const float4*)(src + 4);
    float vv[8] = {v0.x, v0.y, v0.z, v0.w, v1.x, v1.y, v1.z, v1.w};
    ushort hi8[8], lo8[8];
#pragma unroll
    for (int j = 0; j < 8; ++j) {
        unsigned u = __float_as_uint(vv[j]);
        unsigned h = (u + 0x7FFF + ((u >> 16) & 1)) >> 16;   // RN bf16
        hi8[j] = (ushort)h;
        float lo = vv[j] - __uint_as_float(h << 16);
        unsigned ul = __float_as_uint(lo);
        lo8[j] = (ushort)((ul + 0x7FFF + ((ul >> 16) & 1)) >> 16);
    }

    const int tb = rowmn >> 6, fr = (rowmn >> 4) & 3, ml = rowmn & 15;
    ushort* P = isA ? Ap : Bp;
    const long base = (long)tb * 98304 + fr * 512 + ml * 8;
#pragma unroll
    for (int s = 0; s < 3; ++s) {
        int kp8 = s * 64 + k8;
        int kt = kp8 >> 3, r8 = kp8 & 7;
        long off = base + (long)kt * 4096 + (r8 >> 2) * 2048 + (r8 & 3) * 128;
        const ushort* sel = isA ? (s == 1 ? lo8 : hi8) : (s == 2 ? lo8 : hi8);
        *(uint4*)(P + off) = *(const uint4*)sel;
    }
}

// ---------------- stage 1: MFMA GEMM, tile 128x64, 8 waves (4m x 2n, 32x32 each) ----------
// 256 blocks, 512 threads -> 2 waves/SIMD (2x R10 occupancy). XCD-aware mapping:
// xcd = bid&7 hosts mb pair {2*xcd, 2*xcd+1} -> per-XCD L2 set = 4 A panels + all B ~ 3.9MB.
__global__ __launch_bounds__(512) void mfma_gemm(const ushort* __restrict__ Ap,
                                                 const ushort* __restrict__ Bp,
                                                 const float* __restrict__ attn_b,
                                                 float* __restrict__ E1,
                                                 float* __restrict__ E2) {
    const int xcd = blockIdx.x & 7;
    const int idx = blockIdx.x >> 3;       // 0..31
    const int mb  = xcd * 2 + (idx >> 4);  // 0..15
    const int nb  = idx & 15;              // 0..15
    __shared__ ushort lds[2][12288];       // per buf: A0 chunk | A1 chunk | B chunk (3x4096)

    const int t = threadIdx.x;             // 0..511
    const int lane = t & 63, w = t >> 6;   // 8 waves
    const int wr = w >> 1, wc = w & 1;     // wave tile 32(m) x 32(n)

    const ushort* A0 = Ap + (long)(mb * 2 + 0) * 98304;
    const ushort* A1 = Ap + (long)(mb * 2 + 1) * 98304;
    const ushort* B0 = Bp + (long)nb * 98304;

    f32x4 acc[2][2];
#pragma unroll
    for (int i = 0; i < 2; ++i)
#pragma unroll
        for (int j = 0; j < 2; ++j)
            acc[i][j] = (f32x4){0.f, 0.f, 0.f, 0.f};

    uint4 st[3];
#define LOADK(kt)                                                  \
    {                                                              \
        st[0] = ((const uint4*)(A0 + (kt) * 4096))[t];             \
        st[1] = ((const uint4*)(A1 + (kt) * 4096))[t];             \
        st[2] = ((const uint4*)(B0 + (kt) * 4096))[t];             \
    }
#define STOREK(bf)                                                 \
    {                                                              \
        uint4* d = (uint4*)lds[bf];                                \
        d[t] = st[0]; d[t + 512] = st[1]; d[t + 1024] = st[2];     \
    }

    LOADK(0);
    STOREK(0);
    __syncthreads();

    for (int kt = 0; kt < 24; ++kt) {
        if (kt < 23) LOADK(kt + 1);
        const ushort* buf = lds[kt & 1];
#pragma unroll
        for (int ks = 0; ks < 2; ++ks) {
            bf16x8 a[2], b[2];
            const int abase = (wr >> 1) * 4096 + ks * 2048 + (wr & 1) * 1024 + lane * 8;
            const int bbase = 8192 + ks * 2048 + wc * 1024 + lane * 8;
            a[0] = *(const bf16x8*)&buf[abase];
            a[1] = *(const bf16x8*)&buf[abase + 512];
            b[0] = *(const bf16x8*)&buf[bbase];
            b[1] = *(const bf16x8*)&buf[bbase + 512];
#pragma unroll
            for (int mf = 0; mf < 2; ++mf)
#pragma unroll
                for (int nf = 0; nf < 2; ++nf)
                    acc[mf][nf] = __builtin_amdgcn_mfma_f32_16x16x32_bf16(
                        a[mf], b[nf], acc[mf][nf], 0, 0, 0);
        }
        if (kt < 23) {
            STOREK((kt + 1) & 1);
            __syncthreads();
        }
    }
#undef LOADK
#undef STOREK

    // epilogue: D col = lane&15, row = (lane>>4)*4 + r  (m89-verified layout)
#pragma unroll
    for (int nf = 0; nf < 2; ++nf) {
        int n = nb * 64 + wc * 32 + nf * 16 + (lane & 15);
        const bool isE1 = (n < 512);
        float* dst = isE1 ? E1 : E2;
        int o = n & 511;
        float bias = isE1 ? attn_b[o] : 0.0f;
#pragma unroll
        for (int mf = 0; mf < 2; ++mf) {
            int ml = mb * 128 + wr * 32 + mf * 16 + ((lane >> 4) << 2);
            int bb = ml >> 8, l = ml & 255;
            long rowoff = ((long)(bb * 8 + (l >> 5)) * 512 + o) * 32 + (l & 31);
#pragma unroll
            for (int r = 0; r < 4; ++r)
                dst[rowoff + r] = fast_exp2(SCALE * (acc[mf][nf][r] + bias));
        }
    }
}

// ---------------- stage 2: partial energies (R4-exact) ----------------
// EP[s][b][i][j] = sum_{o in chunk s (128)} c_o * rcp(1 + E1[b,i,o]*E2[b,j,o])
__global__ __launch_bounds__(256) void energy_kernel(const float* __restrict__ E1,
                                                     const float* __restrict__ E2,
                                                     const float* __restrict__ sW,
                                                     float* __restrict__ EP) {
    const int bid = blockIdx.x;       // 2048 = 8 b * 8 ti * 8 tj * 4 s
    const int s  = bid & 3;
    const int tj = (bid >> 2) & 7;
    const int ti = (bid >> 5) & 7;
    const int b  = bid >> 8;
    __shared__ float p1s[64 * 32];
    __shared__ float p2s[64 * 32];
    __shared__ float csh[128];

    const int t = threadIdx.x;
    const int tx = t & 15, ty = t >> 4;

    if (t < 128) csh[t] = 2.0f * sW[s * 128 + t];

    const float* p1base = E1 + ((long)(b * 8 + ti) * 512 + s * 128) * 32;
    const float* p2base = E2 + ((long)(b * 8 + tj) * 512 + s * 128) * 32;

    float acc00 = 0.f, acc01 = 0.f, acc10 = 0.f, acc11 = 0.f;

    for (int c0 = 0; c0 < 128; c0 += 64) {
        __syncthreads();
        const float4* s1 = (const float4*)(p1base + c0 * 32);
        const float4* s2 = (const float4*)(p2base + c0 * 32);
        float4* d1 = (float4*)p1s;
        float4* d2 = (float4*)p2s;
        d1[t] = s1[t];  d1[256 + t] = s1[256 + t];
        d2[t] = s2[t];  d2[256 + t] = s2[256 + t];
        __syncthreads();
#pragma unroll 8
        for (int hh = 0; hh < 64; ++hh) {
            float c = csh[c0 + hh];
            float2 a  = *(const float2*)&p1s[hh * 32 + ty * 2];
            float2 bj = *(const float2*)&p2s[hh * 32 + tx * 2];
            acc00 = fmaf(c, fast_rcp(fmaf(a.x, bj.x, 1.0f)), acc00);
            acc01 = fmaf(c, fast_rcp(fmaf(a.x, bj.y, 1.0f)), acc01);
            acc10 = fmaf(c, fast_rcp(fmaf(a.y, bj.x, 1.0f)), acc10);
            acc11 = fmaf(c, fast_rcp(fmaf(a.y, bj.y, 1.0f)), acc11);
        }
    }

    float* Eb = EP + (long)s * 524288 + (long)b * 65536 + (ti * 32) * 256 + tj * 32;
    *(float2*)&Eb[(ty * 2 + 0) * 256 + tx * 2] = make_float2(acc00, acc01);
    *(float2*)&Eb[(ty * 2 + 1) * 256 + tx * 2] = make_float2(acc10, acc11);
}

// ---------------- stage 3: combine partials + softmax over i (axis=1) ----------------
__global__ __launch_bounds__(256) void softmax_kernel(const float* __restrict__ P0,
                                                      const float* __restrict__ P1,
                                                      const float* __restrict__ P2,
                                                      const float* __restrict__ P3,
                                                      float* __restrict__ out) {
    const int b  = blockIdx.x >> 4;
    const int jt = blockIdx.x & 15;
    const int t  = threadIdx.x;
    const int jx = t & 15;
    const int iy = t >> 4;
    const long base = (long)b * 65536 + jt * 16 + jx;

    float v[16];
#pragma unroll
    for (int k = 0; k < 16; ++k) {
        long idx = base + (long)(iy + k * 16) * 256;
        v[k] = -(P0[idx] + P1[idx] + P2[idx] + P3[idx]);
    }

    float m = v[0];
#pragma unroll
    for (int k = 1; k < 16; ++k) m = fmaxf(m, v[k]);

    __shared__ float red[256];
    red[t] = m;
    __syncthreads();
    if (t < 128) red[t] = fmaxf(red[t], red[t + 128]);
    __syncthreads();
    if (t < 64) red[t] = fmaxf(red[t], red[t + 64]);
    __syncthreads();
    if (t < 32) red[t] = fmaxf(red[t], red[t + 32]);
    __syncthreads();
    if (t < 16) red[t] = fmaxf(red[t], red[t + 16]);
    __syncthreads();
    m = red[jx];
    __syncthreads();

    float ssum = 0.f;
#pragma unroll
    for (int k = 0; k < 16; ++k) {
        v[k] = fast_exp2((v[k] - m) * LOG2E);
        ssum += v[k];
    }
    red[t] = ssum;
    __syncthreads();
    if (t < 128) red[t] += red[t + 128];
    __syncthreads();
    if (t < 64) red[t] += red[t + 64];
    __syncthreads();
    if (t < 32) red[t] += red[t + 32];
    __syncthreads();
    if (t < 16) red[t] += red[t + 16];
    __syncthreads();
    float inv = fast_rcp(red[jx]);

#pragma unroll
    for (int k = 0; k < 16; ++k) {
        long idx = base + (long)(iy + k * 16) * 256;
        out[idx] = v[k] * inv;
    }
}

extern "C" void kernel_launch(void* const* d_in, const int* in_sizes, int n_in,
                              void* d_out, int out_size, void* d_ws, size_t ws_size,
                              hipStream_t stream) {
    const float* inputs  = (const float*)d_in[0];  // (256, 8, 512)
    const float* attn_W  = (const float*)d_in[1];  // (512, 1024)
    const float* attn_b  = (const float*)d_in[2];  // (512,)
    const float* score_W = (const float*)d_in[3];  // (1, 512)
    float* out = (float*)d_out;                    // (8, 256, 256)

    float* ws = (float*)d_ws;
    float* E1 = ws;                                // 1M f32 exp panel
    float* E2 = ws + (1 << 20);                    // 1M f32
    float* EP = ws + (2 << 20);                    // 4 * 512K f32 partials (8 MB)
    ushort* Ap = (ushort*)(ws + (4 << 20));        // 3.146M bf16
    ushort* Bp = Ap + 3145728;                     // 1.573M bf16

    pack_kernel<<<768, 256, 0, stream>>>(inputs, attn_W, Ap, Bp);
    mfma_gemm<<<256, 512, 0, stream>>>(Ap, Bp, attn_b, E1, E2);
    energy_kernel<<<2048, 256, 0, stream>>>(E1, E2, score_W, EP);
    softmax_kernel<<<128, 256, 0, stream>>>(EP, EP + 524288, EP + 2 * 524288,
                                            EP + 3 * 524288, out);
}

// Round 12
// 62.880 us; speedup vs baseline: 1.2084x; 1.0525x over previous
//
#include <hip/hip_runtime.h>

#define LOG2E 1.4426950408889634f
#define SCALE (2.0f * LOG2E)

__device__ __forceinline__ float fast_exp2(float x) { return __builtin_amdgcn_exp2f(x); }
__device__ __forceinline__ float fast_rcp(float x)  { return __builtin_amdgcn_rcpf(x); }

typedef __attribute__((ext_vector_type(8))) short bf16x8;
typedef __attribute__((ext_vector_type(4))) float f32x4;

// ---------------- stage 0: pack A/B into bf16 hi/lo MFMA fragment panels (v3) ----------
// Logical GEMM: C[m,n] = sum_{kp=0}^{1535} A[m,kp]*B[n,kp]
//   A segs: 0:x_hi 1:x_lo 2:x_hi ; B segs: 0:w_hi 1:w_hi 2:w_lo  (lo*lo dropped)
// Panel layout (ushort): [tb][kt(24)][ks(2)][fr(4)][lane(64)][j(8)], 98304/tb.
// v3: block=(tb, kchunk128). Phase1: coalesced source reads -> convert -> LDS.
// Phase2: linear panel-order writes (consecutive lanes = consecutive 16B). hi chunks
// written to both duplicate kt ranges (A: kt,kt+16 ; B: kt,kt+8) — bit-identical panels.
__global__ __launch_bounds__(256) void pack_kernel(const float* __restrict__ inputs,
                                                   const float* __restrict__ attn_W,
                                                   ushort* __restrict__ Ap,
                                                   ushort* __restrict__ Bp) {
    __shared__ ushort Hs[64 * 136];
    __shared__ ushort Ls[64 * 136];

    const int bid = blockIdx.x;
    const bool isA = bid < 128;
    const int sub = isA ? bid : bid - 128;
    const int tb = sub >> 2;          // A: 0..31, B: 0..15
    const int kc = sub & 3;           // 128-k chunk
    const int t = threadIdx.x;

    // ---- phase 1: read 64 rows x 128 k, convert, stage ----
#pragma unroll
    for (int it = 0; it < 4; ++it) {
        const int u = it * 256 + t;          // 0..1023
        const int row = u >> 4;              // 0..63 (panel row j)
        const int kc8 = u & 15;              // 8-float unit
        const float* src;
        if (isA) {
            int sr = ((tb & 3) * 64 + row) * 8 + (tb >> 2);
            src = inputs + (long)sr * 512 + kc * 128 + kc8 * 8;
        } else {
            int r = (tb & 7) * 64 + row;
            src = attn_W + (long)r * 1024 + (tb >> 3) * 512 + kc * 128 + kc8 * 8;
        }
        float4 v0 = *(const float4*)src;
        float4 v1 = *(const float4*)(src + 4);
        float vv[8] = {v0.x, v0.y, v0.z, v0.w, v1.x, v1.y, v1.z, v1.w};
        ushort hi8[8], lo8[8];
#pragma unroll
        for (int j = 0; j < 8; ++j) {
            unsigned u32 = __float_as_uint(vv[j]);
            unsigned h = (u32 + 0x7FFF + ((u32 >> 16) & 1)) >> 16;   // RN bf16
            hi8[j] = (ushort)h;
            float lo = vv[j] - __uint_as_float(h << 16);
            unsigned ul = __float_as_uint(lo);
            lo8[j] = (ushort)((ul + 0x7FFF + ((ul >> 16) & 1)) >> 16);
        }
        const int lidx = row * 136 + kc8 * 8;
        *(uint4*)&Hs[lidx] = *(const uint4*)hi8;
        *(uint4*)&Ls[lidx] = *(const uint4*)lo8;
    }
    __syncthreads();

    // ---- phase 2: emit panel chunks in linear panel order ----
    ushort* P = (isA ? Ap : Bp) + (long)tb * 98304;
#pragma unroll
    for (int it = 0; it < 4; ++it) {
        const int u = it * 256 + t;          // 0..1023
        const int l  = u & 63;
        const int fr = (u >> 6) & 3;
        const int ks = (u >> 8) & 1;
        const int ktl = (u >> 9) & 1;
        const int j = fr * 16 + (l & 15);
        const int klocal = ktl * 64 + ks * 32 + (l >> 4) * 8;
        uint4 h  = *(const uint4*)&Hs[j * 136 + klocal];
        uint4 lo = *(const uint4*)&Ls[j * 136 + klocal];
        const int kt0 = kc * 2 + ktl;
        const long off = (long)ks * 2048 + fr * 512 + l * 8;
        if (isA) {
            *(uint4*)(P + (kt0 +  0) * 4096 + off) = h;
            *(uint4*)(P + (kt0 + 16) * 4096 + off) = h;
            *(uint4*)(P + (kt0 +  8) * 4096 + off) = lo;
        } else {
            *(uint4*)(P + (kt0 +  0) * 4096 + off) = h;
            *(uint4*)(P + (kt0 +  8) * 4096 + off) = h;
            *(uint4*)(P + (kt0 + 16) * 4096 + off) = lo;
        }
    }
}

// ---------------- stage 1: MFMA GEMM, tile 128x64, 8 waves (4m x 2n, 32x32 each) ----------
__global__ __launch_bounds__(512) void mfma_gemm(const ushort* __restrict__ Ap,
                                                 const ushort* __restrict__ Bp,
                                                 const float* __restrict__ attn_b,
                                                 float* __restrict__ E1,
                                                 float* __restrict__ E2) {
    const int xcd = blockIdx.x & 7;
    const int idx = blockIdx.x >> 3;       // 0..31
    const int mb  = xcd * 2 + (idx >> 4);  // 0..15
    const int nb  = idx & 15;              // 0..15
    __shared__ ushort lds[2][12288];       // per buf: A0 chunk | A1 chunk | B chunk (3x4096)

    const int t = threadIdx.x;             // 0..511
    const int lane = t & 63, w = t >> 6;   // 8 waves
    const int wr = w >> 1, wc = w & 1;     // wave tile 32(m) x 32(n)

    const ushort* A0 = Ap + (long)(mb * 2 + 0) * 98304;
    const ushort* A1 = Ap + (long)(mb * 2 + 1) * 98304;
    const ushort* B0 = Bp + (long)nb * 98304;

    f32x4 acc[2][2];
#pragma unroll
    for (int i = 0; i < 2; ++i)
#pragma unroll
        for (int j = 0; j < 2; ++j)
            acc[i][j] = (f32x4){0.f, 0.f, 0.f, 0.f};

    uint4 st[3];
#define LOADK(kt)                                                  \
    {                                                              \
        st[0] = ((const uint4*)(A0 + (kt) * 4096))[t];             \
        st[1] = ((const uint4*)(A1 + (kt) * 4096))[t];             \
        st[2] = ((const uint4*)(B0 + (kt) * 4096))[t];             \
    }
#define STOREK(bf)                                                 \
    {                                                              \
        uint4* d = (uint4*)lds[bf];                                \
        d[t] = st[0]; d[t + 512] = st[1]; d[t + 1024] = st[2];     \
    }

    LOADK(0);
    STOREK(0);
    __syncthreads();

    for (int kt = 0; kt < 24; ++kt) {
        if (kt < 23) LOADK(kt + 1);
        const ushort* buf = lds[kt & 1];
#pragma unroll
        for (int ks = 0; ks < 2; ++ks) {
            bf16x8 a[2], b[2];
            const int abase = (wr >> 1) * 4096 + ks * 2048 + (wr & 1) * 1024 + lane * 8;
            const int bbase = 8192 + ks * 2048 + wc * 1024 + lane * 8;
            a[0] = *(const bf16x8*)&buf[abase];
            a[1] = *(const bf16x8*)&buf[abase + 512];
            b[0] = *(const bf16x8*)&buf[bbase];
            b[1] = *(const bf16x8*)&buf[bbase + 512];
#pragma unroll
            for (int mf = 0; mf < 2; ++mf)
#pragma unroll
                for (int nf = 0; nf < 2; ++nf)
                    acc[mf][nf] = __builtin_amdgcn_mfma_f32_16x16x32_bf16(
                        a[mf], b[nf], acc[mf][nf], 0, 0, 0);
        }
        if (kt < 23) {
            STOREK((kt + 1) & 1);
            __syncthreads();
        }
    }
#undef LOADK
#undef STOREK

    // epilogue: D col = lane&15, row = (lane>>4)*4 + r  (m89-verified layout)
#pragma unroll
    for (int nf = 0; nf < 2; ++nf) {
        int n = nb * 64 + wc * 32 + nf * 16 + (lane & 15);
        const bool isE1 = (n < 512);
        float* dst = isE1 ? E1 : E2;
        int o = n & 511;
        float bias = isE1 ? attn_b[o] : 0.0f;
#pragma unroll
        for (int mf = 0; mf < 2; ++mf) {
            int ml = mb * 128 + wr * 32 + mf * 16 + ((lane >> 4) << 2);
            int bb = ml >> 8, l = ml & 255;
            long rowoff = ((long)(bb * 8 + (l >> 5)) * 512 + o) * 32 + (l & 31);
#pragma unroll
            for (int r = 0; r < 4; ++r)
                dst[rowoff + r] = fast_exp2(SCALE * (acc[mf][nf][r] + bias));
        }
    }
}

// ---------------- stage 2: partial energies (R4-exact) ----------------
// EP[s][b][i][j] = sum_{o in chunk s (128)} c_o * rcp(1 + E1[b,i,o]*E2[b,j,o])
__global__ __launch_bounds__(256) void energy_kernel(const float* __restrict__ E1,
                                                     const float* __restrict__ E2,
                                                     const float* __restrict__ sW,
                                                     float* __restrict__ EP) {
    const int bid = blockIdx.x;       // 2048 = 8 b * 8 ti * 8 tj * 4 s
    const int s  = bid & 3;
    const int tj = (bid >> 2) & 7;
    const int ti = (bid >> 5) & 7;
    const int b  = bid >> 8;
    __shared__ float p1s[64 * 32];
    __shared__ float p2s[64 * 32];
    __shared__ float csh[128];

    const int t = threadIdx.x;
    const int tx = t & 15, ty = t >> 4;

    if (t < 128) csh[t] = 2.0f * sW[s * 128 + t];

    const float* p1base = E1 + ((long)(b * 8 + ti) * 512 + s * 128) * 32;
    const float* p2base = E2 + ((long)(b * 8 + tj) * 512 + s * 128) * 32;

    float acc00 = 0.f, acc01 = 0.f, acc10 = 0.f, acc11 = 0.f;

    for (int c0 = 0; c0 < 128; c0 += 64) {
        __syncthreads();
        const float4* s1 = (const float4*)(p1base + c0 * 32);
        const float4* s2 = (const float4*)(p2base + c0 * 32);
        float4* d1 = (float4*)p1s;
        float4* d2 = (float4*)p2s;
        d1[t] = s1[t];  d1[256 + t] = s1[256 + t];
        d2[t] = s2[t];  d2[256 + t] = s2[256 + t];
        __syncthreads();
#pragma unroll 8
        for (int hh = 0; hh < 64; ++hh) {
            float c = csh[c0 + hh];
            float2 a  = *(const float2*)&p1s[hh * 32 + ty * 2];
            float2 bj = *(const float2*)&p2s[hh * 32 + tx * 2];
            acc00 = fmaf(c, fast_rcp(fmaf(a.x, bj.x, 1.0f)), acc00);
            acc01 = fmaf(c, fast_rcp(fmaf(a.x, bj.y, 1.0f)), acc01);
            acc10 = fmaf(c, fast_rcp(fmaf(a.y, bj.x, 1.0f)), acc10);
            acc11 = fmaf(c, fast_rcp(fmaf(a.y, bj.y, 1.0f)), acc11);
        }
    }

    float* Eb = EP + (long)s * 524288 + (long)b * 65536 + (ti * 32) * 256 + tj * 32;
    *(float2*)&Eb[(ty * 2 + 0) * 256 + tx * 2] = make_float2(acc00, acc01);
    *(float2*)&Eb[(ty * 2 + 1) * 256 + tx * 2] = make_float2(acc10, acc11);
}

// ---------------- stage 3: combine partials + softmax over i (axis=1) ----------------
__global__ __launch_bounds__(256) void softmax_kernel(const float* __restrict__ P0,
                                                      const float* __restrict__ P1,
                                                      const float* __restrict__ P2,
                                                      const float* __restrict__ P3,
                                                      float* __restrict__ out) {
    const int b  = blockIdx.x >> 4;
    const int jt = blockIdx.x & 15;
    const int t  = threadIdx.x;
    const int jx = t & 15;
    const int iy = t >> 4;
    const long base = (long)b * 65536 + jt * 16 + jx;

    float v[16];
#pragma unroll
    for (int k = 0; k < 16; ++k) {
        long idx = base + (long)(iy + k * 16) * 256;
        v[k] = -(P0[idx] + P1[idx] + P2[idx] + P3[idx]);
    }

    float m = v[0];
#pragma unroll
    for (int k = 1; k < 16; ++k) m = fmaxf(m, v[k]);

    __shared__ float red[256];
    red[t] = m;
    __syncthreads();
    if (t < 128) red[t] = fmaxf(red[t], red[t + 128]);
    __syncthreads();
    if (t < 64) red[t] = fmaxf(red[t], red[t + 64]);
    __syncthreads();
    if (t < 32) red[t] = fmaxf(red[t], red[t + 32]);
    __syncthreads();
    if (t < 16) red[t] = fmaxf(red[t], red[t + 16]);
    __syncthreads();
    m = red[jx];
    __syncthreads();

    float ssum = 0.f;
#pragma unroll
    for (int k = 0; k < 16; ++k) {
        v[k] = fast_exp2((v[k] - m) * LOG2E);
        ssum += v[k];
    }
    red[t] = ssum;
    __syncthreads();
    if (t < 128) red[t] += red[t + 128];
    __syncthreads();
    if (t < 64) red[t] += red[t + 64];
    __syncthreads();
    if (t < 32) red[t] += red[t + 32];
    __syncthreads();
    if (t < 16) red[t] += red[t + 16];
    __syncthreads();
    float inv = fast_rcp(red[jx]);

#pragma unroll
    for (int k = 0; k < 16; ++k) {
        long idx = base + (long)(iy + k * 16) * 256;
        out[idx] = v[k] * inv;
    }
}

extern "C" void kernel_launch(void* const* d_in, const int* in_sizes, int n_in,
                              void* d_out, int out_size, void* d_ws, size_t ws_size,
                              hipStream_t stream) {
    const float* inputs  = (const float*)d_in[0];  // (256, 8, 512)
    const float* attn_W  = (const float*)d_in[1];  // (512, 1024)
    const float* attn_b  = (const float*)d_in[2];  // (512,)
    const float* score_W = (const float*)d_in[3];  // (1, 512)
    float* out = (float*)d_out;                    // (8, 256, 256)

    float* ws = (float*)d_ws;
    float* E1 = ws;                                // 1M f32 exp panel
    float* E2 = ws + (1 << 20);                    // 1M f32
    float* EP = ws + (2 << 20);                    // 4 * 512K f32 partials (8 MB)
    ushort* Ap = (ushort*)(ws + (4 << 20));        // 3.146M bf16
    ushort* Bp = Ap + 3145728;                     // 1.573M bf16

    pack_kernel<<<192, 256, 0, stream>>>(inputs, attn_W, Ap, Bp);
    mfma_gemm<<<256, 512, 0, stream>>>(Ap, Bp, attn_b, E1, E2);
    energy_kernel<<<2048, 256, 0, stream>>>(E1, E2, score_W, EP);
    softmax_kernel<<<128, 256, 0, stream>>>(EP, EP + 524288, EP + 2 * 524288,
                                            EP + 3 * 524288, out);
}